// Round 3
// baseline (250.896 us; speedup 1.0000x reference)
//
#include <hip/hip_runtime.h>
#include <stdint.h>

#define NB 4096      // B segments/queries
#define NT 819200    // T entries
#define NI 100000    // num items
#define MUF 3.5f

// ---- workspace layout (bytes) ----
#define CURS_OFF   0u          // int[NI]       : histogram, then cursor
#define OFFS_OFF   400064u     // int[NI+1]     : CSR offsets
#define BSUM_OFF   800128u     // int[196]      : scan block sums
#define ACC_OFF    801152u     // float[NB]     : per-segment accumulator
#define QG_OFF     817536u     // float[NB*128] : Qg = Q[item[b],:]
#define PAIRS_OFF  2914688u    // uint64[NT]    : (w_bits<<32)|segment
#define WS_NEEDED  (2914688u + 8u*NT)   // 9,468,288 B

#define NSCANBLK 196           // ceil(NI/512)

// ============ K0: init — zero curs/acc, build Qg ============
__global__ __launch_bounds__(256) void k_init(const float* __restrict__ Q,
                                              const int* __restrict__ item,
                                              char* __restrict__ ws) {
    int idx = blockIdx.x * 256 + threadIdx.x;
    int* curs = (int*)(ws + CURS_OFF);
    float* acc = (float*)(ws + ACC_OFF);
    float4* Qg4 = (float4*)(ws + QG_OFF);
    const float4* Q4 = (const float4*)Q;
    if (idx < NI) {
        curs[idx] = 0;
        if (idx < NB) acc[idx] = 0.f;
    } else {
        int k = idx - NI;
        if (k < NB * 32) {
            int b = k >> 5, l = k & 31;
            Qg4[k] = Q4[(size_t)item[b] * 32 + l];
        }
    }
}

// ============ K1: histogram items ============
__global__ __launch_bounds__(256) void k_hist(const int* __restrict__ imp_items,
                                              char* __restrict__ ws) {
    int t = blockIdx.x * 256 + threadIdx.x;
    int* curs = (int*)(ws + CURS_OFF);
    atomicAdd(&curs[imp_items[t]], 1);
}

// ============ K2a: per-block exclusive scan (512 bins/block) ============
__global__ __launch_bounds__(512) void k_scan_a(char* __restrict__ ws) {
    __shared__ int sm[512];
    int* curs = (int*)(ws + CURS_OFF);
    int* bsum = (int*)(ws + BSUM_OFF);
    int tid = threadIdx.x;
    int g = blockIdx.x * 512 + tid;
    int v = (g < NI) ? curs[g] : 0;
    sm[tid] = v; __syncthreads();
    for (int off = 1; off < 512; off <<= 1) {
        int x = (tid >= off) ? sm[tid - off] : 0;
        __syncthreads();
        sm[tid] += x;
        __syncthreads();
    }
    if (g < NI) curs[g] = sm[tid] - v;     // local exclusive
    if (tid == 511) bsum[blockIdx.x] = sm[511];
}

// ============ K2b: scan the block sums (196 entries) ============
__global__ __launch_bounds__(256) void k_scan_b(char* __restrict__ ws) {
    __shared__ int sm[256];
    int* bsum = (int*)(ws + BSUM_OFF);
    int tid = threadIdx.x;
    int v = (tid < NSCANBLK) ? bsum[tid] : 0;
    sm[tid] = v; __syncthreads();
    for (int off = 1; off < 256; off <<= 1) {
        int x = (tid >= off) ? sm[tid - off] : 0;
        __syncthreads();
        sm[tid] += x;
        __syncthreads();
    }
    if (tid < NSCANBLK) bsum[tid] = sm[tid] - v;  // exclusive
}

// ============ K2c: add block prefix -> offs + curs ============
__global__ __launch_bounds__(512) void k_scan_c(char* __restrict__ ws) {
    int* curs = (int*)(ws + CURS_OFF);
    int* offs = (int*)(ws + OFFS_OFF);
    int* bsum = (int*)(ws + BSUM_OFF);
    int g = blockIdx.x * 512 + threadIdx.x;
    if (g < NI) {
        int val = curs[g] + bsum[blockIdx.x];
        curs[g] = val;
        offs[g] = val;
    }
    if (g == 0) offs[NI] = NT;
}

// ============ K3: fill CSR pairs (segment, w) ============
__global__ __launch_bounds__(256) void k_fill(const float* __restrict__ bu,
                                              const float* __restrict__ bi,
                                              const int* __restrict__ user,
                                              const int* __restrict__ imp_items,
                                              const int* __restrict__ imp_ratings,
                                              const int* __restrict__ seg,
                                              char* __restrict__ ws) {
    int t = blockIdx.x * 256 + threadIdx.x;
    int* curs = (int*)(ws + CURS_OFF);
    uint64_t* pairs = (uint64_t*)(ws + PAIRS_OFF);
    int j = imp_items[t];
    int b = seg[t];
    float w = (float)imp_ratings[t] - MUF - bu[user[b]] - bi[j];
    int pos = atomicAdd(&curs[j], 1);
    pairs[pos] = ((uint64_t)__float_as_uint(w) << 32) | (uint32_t)b;
}

// ============ K4: main — one wave per item, streaming X/Y ============
__global__ __launch_bounds__(256) void k_main(const float* __restrict__ X,
                                              const float* __restrict__ Y,
                                              char* __restrict__ ws) {
    const int tid  = threadIdx.x;
    const int wid  = blockIdx.x * 4 + (tid >> 6);   // item index
    const int lane = tid & 63;
    const int half = lane >> 5;      // 0 -> X part, 1 -> Y part
    const int l    = lane & 31;      // float4 slot in the 128-dim row

    const int* offs = (const int*)(ws + OFFS_OFF);
    const uint64_t* pairs = (const uint64_t*)(ws + PAIRS_OFF);
    const float4* Qg4 = (const float4*)(ws + QG_OFF);
    float* acc = (float*)(ws + ACC_OFF);

    const int s = offs[wid];
    const int e = offs[wid + 1];
    if (s == e) return;

    const float4* R4 = half ? (const float4*)Y : (const float4*)X;
    const float4 r4 = R4[(size_t)wid * 32 + l];

    uint64_t p = pairs[s];
    for (int o = s; o < e; ++o) {
        uint64_t pn = (o + 1 < e) ? pairs[o + 1] : 0;   // prefetch
        const int   b = (int)(p & 0xffffffffu);
        const float w = __uint_as_float((uint32_t)(p >> 32));
        const float4 q4 = Qg4[(size_t)b * 32 + l];
        float pl = q4.x * r4.x + q4.y * r4.y + q4.z * r4.z + q4.w * r4.w;
        float val = half ? pl : w * pl;
        #pragma unroll
        for (int off = 32; off > 0; off >>= 1)
            val += __shfl_down(val, off, 64);
        if (lane == 0) atomicAdd(&acc[b], val);
        p = pn;
    }
}

// ============ K5: finalize ============
__global__ __launch_bounds__(256) void k_final(const float* __restrict__ bu,
                                               const float* __restrict__ bi,
                                               const int* __restrict__ user,
                                               const int* __restrict__ item,
                                               const int* __restrict__ seg,
                                               const char* __restrict__ ws,
                                               float* __restrict__ out) {
    int b = blockIdx.x * 256 + threadIdx.x;
    if (b >= NB) return;
    const float* acc = (const float*)(ws + ACC_OFF);
    auto lower = [&](int key) {
        int lo = 0, hi = NT;
        while (lo < hi) {
            int mid = (lo + hi) >> 1;
            if (seg[mid] < key) lo = mid + 1; else hi = mid;
        }
        return lo;
    };
    int count = lower(b + 1) - lower(b);
    float norm = (count > 0) ? rsqrtf((float)count) : 1.0f;
    out[b] = MUF + bu[user[b]] + bi[item[b]] + norm * acc[b];
}

// ============ fallback (round-1 kernel) if ws too small ============
__global__ __launch_bounds__(256) void asvd_fallback(
    const float* __restrict__ bu, const float* __restrict__ bi,
    const float* __restrict__ Q,  const float* __restrict__ X,
    const float* __restrict__ Y,
    const int* __restrict__ user, const int* __restrict__ item,
    const int* __restrict__ imp_items, const int* __restrict__ imp_ratings,
    const int* __restrict__ seg, float* __restrict__ out)
{
    const int b   = blockIdx.x;
    const int tid = threadIdx.x;
    auto lower = [&](int key) {
        int lo = 0, hi = NT;
        while (lo < hi) {
            int mid = (lo + hi) >> 1;
            if (seg[mid] < key) lo = mid + 1; else hi = mid;
        }
        return lo;
    };
    const int start = lower(b);
    const int end   = lower(b + 1);
    const int count = end - start;
    const int   u    = user[b];
    const int   it   = item[b];
    const float bu_u = bu[u];
    const float bui  = MUF + bu_u + bi[it];
    const int g = tid >> 5;
    const int l = tid & 31;
    const float4* X4 = (const float4*)X;
    const float4* Y4 = (const float4*)Y;
    const float4* Q4 = (const float4*)Q;
    float4 acc = make_float4(0.f, 0.f, 0.f, 0.f);
    for (int t = start + g; t < end; t += 8) {
        const int   j = imp_items[t];
        const float w = (float)imp_ratings[t] - MUF - bu_u - bi[j];
        const float4 x = X4[(size_t)j * 32 + l];
        const float4 y = Y4[(size_t)j * 32 + l];
        acc.x += w * x.x + y.x;  acc.y += w * x.y + y.y;
        acc.z += w * x.z + y.z;  acc.w += w * x.w + y.w;
    }
    const float4 q = Q4[(size_t)it * 32 + l];
    float partial = acc.x * q.x + acc.y * q.y + acc.z * q.z + acc.w * q.w;
    #pragma unroll
    for (int off = 32; off > 0; off >>= 1)
        partial += __shfl_down(partial, off, 64);
    __shared__ float red[4];
    if ((tid & 63) == 0) red[tid >> 6] = partial;
    __syncthreads();
    if (tid == 0) {
        const float total = red[0] + red[1] + red[2] + red[3];
        const float norm  = (count > 0) ? rsqrtf((float)count) : 1.0f;
        out[b] = bui + norm * total;
    }
}

extern "C" void kernel_launch(void* const* d_in, const int* in_sizes, int n_in,
                              void* d_out, int out_size, void* d_ws, size_t ws_size,
                              hipStream_t stream) {
    const float* bu = (const float*)d_in[0];
    const float* bi = (const float*)d_in[1];
    const float* Q  = (const float*)d_in[2];
    const float* X  = (const float*)d_in[3];
    const float* Y  = (const float*)d_in[4];
    const int* user        = (const int*)d_in[5];
    const int* item        = (const int*)d_in[6];
    const int* imp_items   = (const int*)d_in[7];
    const int* imp_ratings = (const int*)d_in[8];
    const int* seg         = (const int*)d_in[9];
    float* out = (float*)d_out;

    if (ws_size < (size_t)WS_NEEDED) {
        asvd_fallback<<<NB, 256, 0, stream>>>(bu, bi, Q, X, Y, user, item,
                                              imp_items, imp_ratings, seg, out);
        return;
    }
    char* ws = (char*)d_ws;

    int init_threads = NI + NB * 32;                       // 231072
    k_init<<<(init_threads + 255) / 256, 256, 0, stream>>>(Q, item, ws);
    k_hist<<<NT / 256, 256, 0, stream>>>(imp_items, ws);
    k_scan_a<<<NSCANBLK, 512, 0, stream>>>(ws);
    k_scan_b<<<1, 256, 0, stream>>>(ws);
    k_scan_c<<<NSCANBLK, 512, 0, stream>>>(ws);
    k_fill<<<NT / 256, 256, 0, stream>>>(bu, bi, user, imp_items, imp_ratings, seg, ws);
    k_main<<<NI / 4, 256, 0, stream>>>(X, Y, ws);
    k_final<<<(NB + 255) / 256, 256, 0, stream>>>(bu, bi, user, item, seg, ws, out);
}

// Round 4
// 93.742 us; speedup vs baseline: 2.6765x; 2.6765x over previous
//
#include <hip/hip_runtime.h>
#include <stdint.h>

#define NB 4096      // B
#define NT 819200    // T
#define NI 100000    // num items
#define MUF 3.5f

// ws layout: XYp = uint4[NI*32]  (per item: 32 slots of 8 bf16 = 4 X comps + 4 Y comps)
#define WS_NEEDED ((size_t)NI * 32 * 16)   // 51,200,000 B

__device__ __forceinline__ uint32_t bf16rne(float f) {
    uint32_t u = __float_as_uint(f);
    return (u + 0x7fffu + ((u >> 16) & 1u)) >> 16;
}
__device__ __forceinline__ uint32_t pack2(float a, float b) {
    return bf16rne(a) | (bf16rne(b) << 16);
}
__device__ __forceinline__ float bf_lo(uint32_t v) { return __uint_as_float(v << 16); }
__device__ __forceinline__ float bf_hi(uint32_t v) { return __uint_as_float(v & 0xffff0000u); }

// ============ K0: pack X,Y (fp32) -> XYp (bf16 interleaved) ============
__global__ __launch_bounds__(256) void k_pack(const float* __restrict__ X,
                                              const float* __restrict__ Y,
                                              uint4* __restrict__ XYp) {
    int idx = blockIdx.x * 256 + threadIdx.x;      // over NI*32 slots
    if (idx >= NI * 32) return;
    const float4* X4 = (const float4*)X;
    const float4* Y4 = (const float4*)Y;
    float4 x = X4[idx];
    float4 y = Y4[idx];
    uint4 v;
    v.x = pack2(x.x, x.y);
    v.y = pack2(x.z, x.w);
    v.z = pack2(y.x, y.y);
    v.w = pack2(y.z, y.w);
    XYp[idx] = v;
}

// ============ K1: main — one block per query, gather packed rows ============
__global__ __launch_bounds__(256) void asvd_main(
    const float* __restrict__ bu, const float* __restrict__ bi,
    const float* __restrict__ Q,
    const uint4* __restrict__ XYp,
    const int* __restrict__ user, const int* __restrict__ item,
    const int* __restrict__ imp_items, const int* __restrict__ imp_ratings,
    const int* __restrict__ seg, float* __restrict__ out)
{
    const int b   = blockIdx.x;
    const int tid = threadIdx.x;

    auto lower = [&](int key) {
        int lo = 0, hi = NT;
        while (lo < hi) {
            int mid = (lo + hi) >> 1;
            if (seg[mid] < key) lo = mid + 1; else hi = mid;
        }
        return lo;
    };
    const int start = lower(b);
    const int end   = lower(b + 1);
    const int count = end - start;

    const int   u    = user[b];
    const int   it   = item[b];
    const float bu_u = bu[u];
    const float bui  = MUF + bu_u + bi[it];

    const int g = tid >> 5;   // entry group 0..7
    const int l = tid & 31;   // 16B slot within the packed 512B row

    const int STEP = 8;
    float4 a0 = make_float4(0.f,0.f,0.f,0.f);
    float4 a1 = make_float4(0.f,0.f,0.f,0.f);

    int t = start + g;
    for (; t + STEP < end; t += 2*STEP) {
        const int j0 = imp_items[t];
        const int j1 = imp_items[t + STEP];
        const int r0 = imp_ratings[t];
        const int r1 = imp_ratings[t + STEP];
        const float w0 = (float)r0 - MUF - bu_u - bi[j0];
        const float w1 = (float)r1 - MUF - bu_u - bi[j1];
        const uint4 v0 = XYp[(size_t)j0 * 32 + l];
        const uint4 v1 = XYp[(size_t)j1 * 32 + l];

        a0.x += w0 * bf_lo(v0.x) + bf_lo(v0.z);
        a0.y += w0 * bf_hi(v0.x) + bf_hi(v0.z);
        a0.z += w0 * bf_lo(v0.y) + bf_lo(v0.w);
        a0.w += w0 * bf_hi(v0.y) + bf_hi(v0.w);
        a1.x += w1 * bf_lo(v1.x) + bf_lo(v1.z);
        a1.y += w1 * bf_hi(v1.x) + bf_hi(v1.z);
        a1.z += w1 * bf_lo(v1.y) + bf_lo(v1.w);
        a1.w += w1 * bf_hi(v1.y) + bf_hi(v1.w);
    }
    for (; t < end; t += STEP) {
        const int j = imp_items[t];
        const float w = (float)imp_ratings[t] - MUF - bu_u - bi[j];
        const uint4 v = XYp[(size_t)j * 32 + l];
        a0.x += w * bf_lo(v.x) + bf_lo(v.z);
        a0.y += w * bf_hi(v.x) + bf_hi(v.z);
        a0.z += w * bf_lo(v.y) + bf_lo(v.w);
        a0.w += w * bf_hi(v.y) + bf_hi(v.w);
    }
    a0.x += a1.x; a0.y += a1.y; a0.z += a1.z; a0.w += a1.w;

    const float4* Q4 = (const float4*)Q;
    const float4 q = Q4[(size_t)it * 32 + l];
    float partial = a0.x * q.x + a0.y * q.y + a0.z * q.z + a0.w * q.w;

    #pragma unroll
    for (int off = 32; off > 0; off >>= 1)
        partial += __shfl_down(partial, off, 64);

    __shared__ float red[4];
    if ((tid & 63) == 0) red[tid >> 6] = partial;
    __syncthreads();
    if (tid == 0) {
        const float total = red[0] + red[1] + red[2] + red[3];
        const float norm  = (count > 0) ? rsqrtf((float)count) : 1.0f;
        out[b] = bui + norm * total;
    }
}

// ============ fallback (round-1 kernel) if ws too small ============
__global__ __launch_bounds__(256) void asvd_fallback(
    const float* __restrict__ bu, const float* __restrict__ bi,
    const float* __restrict__ Q,  const float* __restrict__ X,
    const float* __restrict__ Y,
    const int* __restrict__ user, const int* __restrict__ item,
    const int* __restrict__ imp_items, const int* __restrict__ imp_ratings,
    const int* __restrict__ seg, float* __restrict__ out)
{
    const int b   = blockIdx.x;
    const int tid = threadIdx.x;
    auto lower = [&](int key) {
        int lo = 0, hi = NT;
        while (lo < hi) {
            int mid = (lo + hi) >> 1;
            if (seg[mid] < key) lo = mid + 1; else hi = mid;
        }
        return lo;
    };
    const int start = lower(b);
    const int end   = lower(b + 1);
    const int count = end - start;
    const int   u    = user[b];
    const int   it   = item[b];
    const float bu_u = bu[u];
    const float bui  = MUF + bu_u + bi[it];
    const int g = tid >> 5;
    const int l = tid & 31;
    const float4* X4 = (const float4*)X;
    const float4* Y4 = (const float4*)Y;
    const float4* Q4 = (const float4*)Q;
    float4 acc = make_float4(0.f, 0.f, 0.f, 0.f);
    for (int t = start + g; t < end; t += 8) {
        const int   j = imp_items[t];
        const float w = (float)imp_ratings[t] - MUF - bu_u - bi[j];
        const float4 x = X4[(size_t)j * 32 + l];
        const float4 y = Y4[(size_t)j * 32 + l];
        acc.x += w * x.x + y.x;  acc.y += w * x.y + y.y;
        acc.z += w * x.z + y.z;  acc.w += w * x.w + y.w;
    }
    const float4 q = Q4[(size_t)it * 32 + l];
    float partial = acc.x * q.x + acc.y * q.y + acc.z * q.z + acc.w * q.w;
    #pragma unroll
    for (int off = 32; off > 0; off >>= 1)
        partial += __shfl_down(partial, off, 64);
    __shared__ float red[4];
    if ((tid & 63) == 0) red[tid >> 6] = partial;
    __syncthreads();
    if (tid == 0) {
        const float total = red[0] + red[1] + red[2] + red[3];
        const float norm  = (count > 0) ? rsqrtf((float)count) : 1.0f;
        out[b] = bui + norm * total;
    }
}

extern "C" void kernel_launch(void* const* d_in, const int* in_sizes, int n_in,
                              void* d_out, int out_size, void* d_ws, size_t ws_size,
                              hipStream_t stream) {
    const float* bu = (const float*)d_in[0];
    const float* bi = (const float*)d_in[1];
    const float* Q  = (const float*)d_in[2];
    const float* X  = (const float*)d_in[3];
    const float* Y  = (const float*)d_in[4];
    const int* user        = (const int*)d_in[5];
    const int* item        = (const int*)d_in[6];
    const int* imp_items   = (const int*)d_in[7];
    const int* imp_ratings = (const int*)d_in[8];
    const int* seg         = (const int*)d_in[9];
    float* out = (float*)d_out;

    if (ws_size < WS_NEEDED) {
        asvd_fallback<<<NB, 256, 0, stream>>>(bu, bi, Q, X, Y, user, item,
                                              imp_items, imp_ratings, seg, out);
        return;
    }
    uint4* XYp = (uint4*)d_ws;

    k_pack<<<(NI * 32 + 255) / 256, 256, 0, stream>>>(X, Y, XYp);
    asvd_main<<<NB, 256, 0, stream>>>(bu, bi, Q, XYp, user, item,
                                      imp_items, imp_ratings, seg, out);
}